// Round 3
// baseline (384.580 us; speedup 1.0000x reference)
//
#include <hip/hip_runtime.h>

#define NB 64
#define NT 512
#define NH 1024
#define NC 8
#define NK 3
#define BT (NB*NT)             // 32768
#define LOGITS_N (NK*BT*NC)    // 786432

// DPP controls: quad_perm xor1 / xor2; row rotates for xor4/xor8 within 16-lane rows
#define QP1  0xB1   // quad_perm [1,0,3,2]  -> lane^1
#define QP2  0x4E   // quad_perm [2,3,0,1]  -> lane^2
#define ROR4 0x124  // row_ror:4 -> flips lane bit2 (c-bit2), may flip bit3 (dup bit: harmless)
#define ROR8 0x128  // row_ror:8 -> lane^8 within 16-row

template<int CTRL>
__device__ __forceinline__ float dppf(float x) {
  return __int_as_float(__builtin_amdgcn_update_dpp(0, __float_as_int(x), CTRL, 0xF, 0xF, true));
}
template<int CTRL>
__device__ __forceinline__ int dppi(int x) {
  return __builtin_amdgcn_update_dpp(0, x, CTRL, 0xF, 0xF, true);
}

// ---------------- init: zero loss, transpose W -> Wt[h][24] in d_ws --------
__global__ __launch_bounds__(256) void init_kernel(const float* __restrict__ W,
                                                   float* __restrict__ Wt,
                                                   float* __restrict__ out) {
  int i = blockIdx.x * 256 + threadIdx.x;
  if (i < 24 * NH) {
    int h = i / 24, j = i - h * 24;
    int k = j >> 3, c = j & 7;
    Wt[i] = W[k * NC * NH + c * NH + h];   // Wt[h*24 + j] = W[k][c][h]
  }
  if (i == 0) out[0] = 0.0f;
}

// ---------------- proj: 512 blocks x 256 thr; 4 waves each own an H-quarter
// (W stays wave-uniform -> scalar loads); no barriers in main loop.
__global__ __launch_bounds__(256, 2) void proj_kernel(const float* __restrict__ enc,
                                                      const float* __restrict__ Wt,
                                                      const float* __restrict__ bias,
                                                      float* __restrict__ out) {
  __shared__ float sE[4][64 * 36];        // per-wave staging, stride 36 (16B-aligned rows)
  __shared__ float sP[4][64 * 28];        // partials, stride 28
  const int tid = threadIdx.x;
  const int lane = tid & 63;              // = row within block
  const int q = tid >> 6;                 // wave id = h-quarter
  const int row0 = blockIdx.x * 64;

  float acc[24];
#pragma unroll
  for (int j = 0; j < 24; ++j) acc[j] = 0.0f;

  const float* eb = enc + (size_t)row0 * 1024 + q * 256;
  float* sEw = sE[q];

  float4 pf[8];
#pragma unroll
  for (int s = 0; s < 8; ++s) {
    int f = lane + 64 * s;
    pf[s] = *(const float4*)(eb + (f >> 3) * 1024 + (f & 7) * 4);
  }

  for (int ch = 0; ch < 8; ++ch) {
#pragma unroll
    for (int s = 0; s < 8; ++s) {
      int f = lane + 64 * s;
      *(float4*)&sEw[(f >> 3) * 36 + (f & 7) * 4] = pf[s];
    }
    if (ch < 7) {
      int hb = (ch + 1) * 32;
#pragma unroll
      for (int s = 0; s < 8; ++s) {
        int f = lane + 64 * s;
        pf[s] = *(const float4*)(eb + (f >> 3) * 1024 + hb + (f & 7) * 4);
      }
    }
    const float* wrow = Wt + (q * 256 + ch * 32) * 24;   // wave-uniform
#pragma unroll
    for (int h4 = 0; h4 < 32; h4 += 4) {
      float4 e = *(float4*)&sEw[lane * 36 + h4];
      const float* w0 = wrow + h4 * 24;
#pragma unroll
      for (int j = 0; j < 24; ++j) acc[j] = fmaf(e.x, w0[j], acc[j]);
#pragma unroll
      for (int j = 0; j < 24; ++j) acc[j] = fmaf(e.y, w0[24 + j], acc[j]);
#pragma unroll
      for (int j = 0; j < 24; ++j) acc[j] = fmaf(e.z, w0[48 + j], acc[j]);
#pragma unroll
      for (int j = 0; j < 24; ++j) acc[j] = fmaf(e.w, w0[72 + j], acc[j]);
    }
  }

#pragma unroll
  for (int j4 = 0; j4 < 24; j4 += 4) {
    float4 v = make_float4(acc[j4], acc[j4 + 1], acc[j4 + 2], acc[j4 + 3]);
    *(float4*)&sP[q][lane * 28 + j4] = v;
  }
  __syncthreads();

  // combine: thread t -> row r=t>>2, j = (t&3)*6 .. +5
  const int r = tid >> 2, j0 = (tid & 3) * 6;
#pragma unroll
  for (int u = 0; u < 6; ++u) {
    int j = j0 + u;
    float s = sP[0][r * 28 + j] + sP[1][r * 28 + j] + sP[2][r * 28 + j] + sP[3][r * 28 + j]
            + bias[j];
    out[1 + (size_t)(j >> 3) * (BT * 8) + (size_t)(row0 + r) * 8 + (j & 7)] = s;
  }
}

// ---------------- CRF: blocks 0..47 forward+loss, 48..95 viterbi+preds -----
// 1 wave/block; 16 lanes per sequence: c = lane&7 (state), bit3 = duplicate copy.
// All cross-lane traffic via full-rate DPP (QP1/QP2/ROR4), no LDS on the chain.
__global__ __launch_bounds__(64) void crf_kernel(const float* __restrict__ logits,
                                                 const int* __restrict__ labels,
                                                 const float* __restrict__ startT,
                                                 const float* __restrict__ endT,
                                                 const float* __restrict__ trans,
                                                 float* __restrict__ d_out) {
  __shared__ __align__(16) unsigned char sBP[4][512 * 16];
  __shared__ unsigned char sTagsF[4 * 512];

  const int lane = threadIdx.x;
  const int l16 = lane & 15;
  const int s = lane >> 4;                 // seq within wave (4 per wave)
  const int c = l16 & 7;                   // state
  const int role = (blockIdx.x < 48) ? 0 : 1;
  const int sb = role ? (blockIdx.x - 48) : blockIdx.x;
  const int seq = sb * 4 + s;              // 0..191
  const int k = seq >> 6, b = seq & 63;

  const float* em = logits + (size_t)seq * (NT * NC);
  const float* trk = trans + k * 64;

  float Tx[8];
#pragma unroll
  for (int kk = 0; kk < 8; ++kk) Tx[kk] = trk[(c ^ kk) * 8 + c];  // trans[c^kk][c]
  const float startc = startT[k * 8 + c];
  const float endc = endT[k * 8 + c];

  float ecur[8];
#pragma unroll
  for (int i = 0; i < 8; ++i) ecur[i] = em[i * 8 + c];

  if (role == 0) {
    // ---------------- forward (linear domain, normalized every 8) ----------
    float Mx[8];
#pragma unroll
    for (int kk = 0; kk < 8; ++kk) Mx[kk] = __expf(Tx[kk]);
    float alpha = __expf(startc + ecur[0]);
    float logZacc = 0.0f;
    for (int t0 = 0; t0 < 512; t0 += 8) {
      float enext[8];
      if (t0 + 8 < 512) {
#pragma unroll
        for (int i = 0; i < 8; ++i) enext[i] = em[(t0 + 8 + i) * 8 + c];
      } else {
#pragma unroll
        for (int i = 0; i < 8; ++i) enext[i] = 0.0f;
      }
      float ex[8];
#pragma unroll
      for (int i = 0; i < 8; ++i) ex[i] = __expf(ecur[i]);
#pragma unroll
      for (int j = 0; j < 8; ++j) {
        if (t0 == 0 && j == 0) continue;
        float a1 = dppf<QP1>(alpha);       // alpha[c^1]
        float a2 = dppf<QP2>(alpha);       // alpha[c^2]
        float a3 = dppf<QP2>(a1);          // alpha[c^3]
        float a4 = dppf<ROR4>(alpha);      // alpha[c^4]
        float a5 = dppf<ROR4>(a1);         // alpha[c^5]
        float a6 = dppf<ROR4>(a2);         // alpha[c^6]
        float a7 = dppf<ROR4>(a3);         // alpha[c^7]
        float s01 = fmaf(a1, Mx[1], alpha * Mx[0]);
        float s23 = fmaf(a3, Mx[3], a2 * Mx[2]);
        float s45 = fmaf(a5, Mx[5], a4 * Mx[4]);
        float s67 = fmaf(a7, Mx[7], a6 * Mx[6]);
        alpha = ((s01 + s23) + (s45 + s67)) * ex[j];
      }
      float sum = alpha;
      sum += dppf<QP1>(sum);
      sum += dppf<QP2>(sum);
      sum += dppf<ROR4>(sum);             // all 16 lanes hold full 8-state sum
      logZacc += __logf(sum);
      alpha *= (1.0f / sum);
#pragma unroll
      for (int i = 0; i < 8; ++i) ecur[i] = enext[i];
    }
    float se = alpha * __expf(endc);
    se += dppf<QP1>(se);
    se += dppf<QP2>(se);
    se += dppf<ROR4>(se);
    float logZ = logZacc + __logf(se);

    // gold-path numerator: 16 lanes per seq split over t
    const int* lab = labels + b * (NK * NT) + k * NT;
    float nsum = 0.0f;
    for (int i = 0; i < 32; ++i) {
      int t = l16 + i * 16;
      int tg = lab[t];
      nsum += em[t * 8 + tg];
      if (t < 511) nsum += trk[tg * 8 + lab[t + 1]];
    }
    nsum += dppf<QP1>(nsum);
    nsum += dppf<QP2>(nsum);
    nsum += dppf<ROR4>(nsum);
    nsum += dppf<ROR8>(nsum);             // full 16-lane sum
    if (l16 == 0) {
      float num = nsum + startT[k * 8 + lab[0]] + endT[k * 8 + lab[511]];
      atomicAdd(d_out, logZ - num);
    }
  } else {
    // ---------------- viterbi ----------------
    float v = startc + ecur[0];
    int pk[8];
#pragma unroll
    for (int kk = 0; kk < 8; ++kk) pk[kk] = c ^ kk;
    unsigned char* bpg = sBP[s];
    for (int t0 = 0; t0 < 512; t0 += 8) {
      float enext[8];
      if (t0 + 8 < 512) {
#pragma unroll
        for (int i = 0; i < 8; ++i) enext[i] = em[(t0 + 8 + i) * 8 + c];
      } else {
#pragma unroll
        for (int i = 0; i < 8; ++i) enext[i] = 0.0f;
      }
#pragma unroll
      for (int j = 0; j < 8; ++j) {
        if (t0 == 0 && j == 0) continue;
        int t = t0 + j;
        float b1 = dppf<QP1>(v);
        float b2 = dppf<QP2>(v);
        float b3 = dppf<QP2>(b1);
        float b4 = dppf<ROR4>(v);
        float b5 = dppf<ROR4>(b1);
        float b6 = dppf<ROR4>(b2);
        float b7 = dppf<ROR4>(b3);
        float c0 = v + Tx[0], c1 = b1 + Tx[1], c2 = b2 + Tx[2], c3 = b3 + Tx[3];
        float c4 = b4 + Tx[4], c5 = b5 + Tx[5], c6 = b6 + Tx[6], c7 = b7 + Tx[7];
        float m0 = fmaxf(fmaxf(c0, c1), c2);           // -> v_max3
        float m1 = fmaxf(fmaxf(c3, c4), c5);
        float m2 = fmaxf(c6, c7);
        float best = fmaxf(fmaxf(m0, m1), m2);
        // exact first-p tie-break: min prev-state index among equals
        int a0 = (c0 == best) ? pk[0] : 8;
        int a1i = (c1 == best) ? pk[1] : 8;
        int a2i = (c2 == best) ? pk[2] : 8;
        int a3i = (c3 == best) ? pk[3] : 8;
        int a4i = (c4 == best) ? pk[4] : 8;
        int a5i = (c5 == best) ? pk[5] : 8;
        int a6i = (c6 == best) ? pk[6] : 8;
        int a7i = (c7 == best) ? pk[7] : 8;
        int arg = min(min(min(a0, a1i), min(a2i, a3i)),
                      min(min(a4i, a5i), min(a6i, a7i)));
        v = best + ecur[j];
        bpg[t * 16 + l16] = (unsigned char)arg;        // dup lanes write bytes 8..15 (unused)
      }
#pragma unroll
      for (int i = 0; i < 8; ++i) ecur[i] = enext[i];
    }
    // terminal argmax (first max on ties) across 8 states
    float lv = v + endc;
    int li = c;
    {
      float ov; int oi; bool take;
      ov = dppf<QP1>(lv); oi = dppi<QP1>(li);
      take = (ov > lv) || (ov == lv && oi < li); lv = take ? ov : lv; li = take ? oi : li;
      ov = dppf<QP2>(lv); oi = dppi<QP2>(li);
      take = (ov > lv) || (ov == lv && oi < li); lv = take ? ov : lv; li = take ? oi : li;
      ov = dppf<ROR4>(lv); oi = dppi<ROR4>(li);
      take = (ov > lv) || (ov == lv && oi < li); lv = take ? ov : lv; li = take ? oi : li;
    }
    __syncthreads();
    if (l16 == 0) {
      int tag = li;
      sTagsF[s * 512 + 511] = (unsigned char)tag;
      int t = 511;
      while (t >= 1) {
        int n = (t >= 8) ? 8 : t;
        unsigned long long rows[8];
#pragma unroll
        for (int i = 0; i < 8; ++i)
          if (i < n) rows[i] = *(const unsigned long long*)&bpg[(t - i) * 16];
#pragma unroll
        for (int i = 0; i < 8; ++i)
          if (i < n) {
            tag = (int)((rows[i] >> (tag * 8)) & 7ULL);
            sTagsF[s * 512 + t - i - 1] = (unsigned char)tag;
          }
        t -= n;
      }
    }
    __syncthreads();
    float* outp = d_out + 1 + LOGITS_N + (size_t)sb * 2048;
    for (int u = 0; u < 32; ++u) {
      int idx = u * 64 + lane;
      outp[idx] = (float)sTagsF[idx];
    }
  }
}

extern "C" void kernel_launch(void* const* d_in, const int* in_sizes, int n_in,
                              void* d_out, int out_size, void* d_ws, size_t ws_size,
                              hipStream_t stream) {
  const float* enc    = (const float*)d_in[0];
  const int*   labels = (const int*)  d_in[1];
  const float* W      = (const float*)d_in[2];
  const float* bias   = (const float*)d_in[3];
  const float* startT = (const float*)d_in[4];
  const float* endT   = (const float*)d_in[5];
  const float* trans  = (const float*)d_in[6];
  float* out = (float*)d_out;
  float* Wt  = (float*)d_ws;   // 24*1024 floats = 96 KB scratch

  init_kernel<<<dim3(96), dim3(256), 0, stream>>>(W, Wt, out);
  proj_kernel<<<dim3(512), dim3(256), 0, stream>>>(enc, Wt, bias, out);
  crf_kernel<<<dim3(96), dim3(64), 0, stream>>>(out + 1, labels, startT, endT, trans, out);
}

// Round 4
// 374.320 us; speedup vs baseline: 1.0274x; 1.0274x over previous
//
#include <hip/hip_runtime.h>

#define NB 64
#define NT 512
#define NH 1024
#define NC 8
#define NK 3
#define BT (NB*NT)             // 32768
#define LOGITS_N (NK*BT*NC)    // 786432

// DPP controls
#define QP1  0xB1   // quad_perm [1,0,3,2] -> lane^1
#define QP2  0x4E   // quad_perm [2,3,0,1] -> lane^2
#define ROR4 0x124  // row_ror:4 -> flips lane bit2; bit3 (dup) flip harmless
#define ROR8 0x128  // row_ror:8 -> lane^8 within 16-row

template<int CTRL>
__device__ __forceinline__ float dppf(float x) {
  return __int_as_float(__builtin_amdgcn_update_dpp(0, __float_as_int(x), CTRL, 0xF, 0xF, true));
}
template<int CTRL>
__device__ __forceinline__ int dppi(int x) {
  return __builtin_amdgcn_update_dpp(0, x, CTRL, 0xF, 0xF, true);
}

// ---------- init: bias into logits, zero loss, transpose W -> Wt[h][24] ----
__global__ __launch_bounds__(256) void init_kernel(const float* __restrict__ W,
                                                   const float* __restrict__ bias,
                                                   float* __restrict__ Wt,
                                                   float* __restrict__ out) {
  int i = blockIdx.x * 256 + threadIdx.x;
  if (i < LOGITS_N) {
    int k = i >> 18, c = i & 7;
    out[1 + i] = bias[k * 8 + c];
  }
  if (i < 24 * NH) {
    int h = i / 24, j = i - h * 24;
    int kk = j >> 3, cc = j & 7;
    Wt[i] = W[kk * NC * NH + cc * NH + h];   // Wt[h*24 + j]
  }
  if (i == 0) out[0] = 0.0f;
}

// ---------- proj: grid 256 = 128 rowblocks x 2 h-halves; 256 thr, 1 row/thr.
// W addresses depend ONLY on blockIdx/loop constants -> uniform -> s_load.
__global__ __launch_bounds__(256) void proj_kernel(const float* __restrict__ enc,
                                                   const float* __restrict__ Wt,
                                                   float* __restrict__ out) {
  __shared__ float sE[2][256 * 19];        // stride 19: conflict-free reads
  const int tid = threadIdx.x;
  const int hs = blockIdx.x & 1;
  const int rb = blockIdx.x >> 1;
  const int row0 = rb * 256;
  const float* eb = enc + (size_t)row0 * 1024 + hs * 512;

  float acc[24];
#pragma unroll
  for (int j = 0; j < 24; ++j) acc[j] = 0.0f;

  float4 pf[4];
  // load chunk 0
#pragma unroll
  for (int s = 0; s < 4; ++s) {
    int f = tid + 256 * s;
    pf[s] = *(const float4*)(eb + (size_t)(f >> 2) * 1024 + (f & 3) * 4);
  }
  // write chunk 0 -> buf0
#pragma unroll
  for (int s = 0; s < 4; ++s) {
    int f = tid + 256 * s;
    float* d = &sE[0][(f >> 2) * 19 + (f & 3) * 4];
    d[0] = pf[s].x; d[1] = pf[s].y; d[2] = pf[s].z; d[3] = pf[s].w;
  }
  // load chunk 1
#pragma unroll
  for (int s = 0; s < 4; ++s) {
    int f = tid + 256 * s;
    pf[s] = *(const float4*)(eb + (size_t)(f >> 2) * 1024 + 16 + (f & 3) * 4);
  }
  __syncthreads();

#pragma unroll 1
  for (int ch = 0; ch < 32; ++ch) {
    const int buf = ch & 1;
    const float* wrow = Wt + (hs * 512 + ch * 16) * 24;   // block-uniform
#pragma unroll 4
    for (int h = 0; h < 16; ++h) {
      float e = sE[buf][tid * 19 + h];
#pragma unroll
      for (int j = 0; j < 24; ++j)
        acc[j] = fmaf(e, wrow[h * 24 + j], acc[j]);
    }
    if (ch < 31) {
      // stage chunk ch+1 (held in pf) into the other buffer
#pragma unroll
      for (int s = 0; s < 4; ++s) {
        int f = tid + 256 * s;
        float* d = &sE[buf ^ 1][(f >> 2) * 19 + (f & 3) * 4];
        d[0] = pf[s].x; d[1] = pf[s].y; d[2] = pf[s].z; d[3] = pf[s].w;
      }
      if (ch < 30) {
#pragma unroll
        for (int s = 0; s < 4; ++s) {
          int f = tid + 256 * s;
          pf[s] = *(const float4*)(eb + (size_t)(f >> 2) * 1024 + (ch + 2) * 16 + (f & 3) * 4);
        }
      }
      __syncthreads();
    }
  }

  // combine the two h-halves via fire-and-forget atomics (bias pre-written)
  const int row = row0 + tid;
#pragma unroll
  for (int k = 0; k < 3; ++k)
#pragma unroll
    for (int c = 0; c < 8; ++c)
      atomicAdd(&out[1 + (size_t)k * (BT * 8) + (size_t)row * 8 + c], acc[k * 8 + c]);
}

// ---------- CRF: blocks 0..47 forward+loss, 48..95 viterbi+preds ----------
// 1 wave/block; 16 lanes/seq (c = lane&7, bit3 = dup), 4 seqs/wave.
// Emissions staged in LDS (4 regions of 128 t, double-buffered) -> chains
// never touch global memory.
__global__ __launch_bounds__(64) void crf_kernel(const int* __restrict__ labels,
                                                 const float* __restrict__ startT,
                                                 const float* __restrict__ endT,
                                                 const float* __restrict__ trans,
                                                 float* __restrict__ d_out) {
  __shared__ float sEm[2][128 * 32];       // [buf][(t'*4+s)*8+c]  32 KB
  __shared__ int sBPp[512 * 4];            // vit: packed 3-bit args [t][s]  8 KB
  __shared__ unsigned char sTags[2048];    // vit: [s*512+t]  2 KB

  const int lane = threadIdx.x;
  const int l16 = lane & 15;
  const int s = lane >> 4;
  const int c = l16 & 7;
  const int role = (blockIdx.x < 48) ? 0 : 1;
  const int sb = role ? (blockIdx.x - 48) : blockIdx.x;
  const int seq = sb * 4 + s;
  const int k = seq >> 6, b = seq & 63;

  const float* out1 = d_out + 1;
  const float* embase = out1 + (size_t)k * (BT * 8) + (size_t)(b * 512) * 8;
  const float* trk = trans + k * 64;

  float Tx[8];
#pragma unroll
  for (int kk = 0; kk < 8; ++kk) Tx[kk] = trk[(c ^ kk) * 8 + c];
  const float startc = startT[k * 8 + c];
  const float endc = endT[k * 8 + c];

  float4 pre[16];
  auto loadRegion = [&](int r) {
#pragma unroll
    for (int u = 0; u < 16; ++u) {
      int f = u * 16 + l16;
      int t = r * 128 + (f >> 1);
      const float* o = embase + (size_t)t * 8 + (f & 1) * 4;
      pre[u] = make_float4(o[0], o[1], o[2], o[3]);
    }
  };
  auto writeRegion = [&](int buf) {
    float* dst = sEm[buf];
#pragma unroll
    for (int u = 0; u < 16; ++u) {
      int f = u * 16 + l16;
      *(float4*)&dst[((f >> 1) * 4 + s) * 8 + (f & 1) * 4] = pre[u];
    }
  };

  loadRegion(0);
  writeRegion(0);
  loadRegion(1);

  float ecur[8];
#pragma unroll
  for (int i = 0; i < 8; ++i) ecur[i] = sEm[0][(i * 4 + s) * 8 + c];

  if (role == 0) {
    // ------------- forward (linear domain, normalized every 8) -------------
    float Mx[8];
#pragma unroll
    for (int kk = 0; kk < 8; ++kk) Mx[kk] = __expf(Tx[kk]);
    float alpha = __expf(startc + ecur[0]);
    float logZacc = 0.0f, nsum = 0.0f;
    const int* lab = labels + b * (NK * NT) + k * NT;

#pragma unroll 1
    for (int r = 0; r < 4; ++r) {
      if (r < 3) writeRegion((r + 1) & 1);
      if (r < 2) loadRegion(r + 2);
#pragma unroll 1
      for (int t0 = r * 128; t0 < r * 128 + 128; t0 += 8) {
        float enext[8];
        if (t0 + 8 < 512) {
          const float* rg = sEm[((t0 + 8) >> 7) & 1];
#pragma unroll
          for (int i = 0; i < 8; ++i) enext[i] = rg[(((t0 + 8 + i) & 127) * 4 + s) * 8 + c];
        } else {
#pragma unroll
          for (int i = 0; i < 8; ++i) enext[i] = 0.0f;
        }
        float ex[8];
#pragma unroll
        for (int i = 0; i < 8; ++i) ex[i] = __expf(ecur[i]);
#pragma unroll
        for (int j = 0; j < 8; ++j) {
          if (t0 == 0 && j == 0) continue;
          float a1 = dppf<QP1>(alpha), a2 = dppf<QP2>(alpha), a3 = dppf<QP2>(a1);
          float a4 = dppf<ROR4>(alpha), a5 = dppf<ROR4>(a1);
          float a6 = dppf<ROR4>(a2), a7 = dppf<ROR4>(a3);
          float s01 = fmaf(a1, Mx[1], alpha * Mx[0]);
          float s23 = fmaf(a3, Mx[3], a2 * Mx[2]);
          float s45 = fmaf(a5, Mx[5], a4 * Mx[4]);
          float s67 = fmaf(a7, Mx[7], a6 * Mx[6]);
          alpha = ((s01 + s23) + (s45 + s67)) * ex[j];
        }
        float sum = alpha;
        sum += dppf<QP1>(sum); sum += dppf<QP2>(sum); sum += dppf<ROR4>(sum);
        logZacc += __logf(sum);
        alpha *= (1.0f / sum);
#pragma unroll
        for (int i = 0; i < 8; ++i) ecur[i] = enext[i];
      }
      // gold-path emissions/transitions for this region (from LDS)
      const float* rg = sEm[r & 1];
#pragma unroll 1
      for (int i = 0; i < 8; ++i) {
        int t = r * 128 + l16 + i * 16;
        int tg = lab[t];
        nsum += rg[((t & 127) * 4 + s) * 8 + tg];
        if (t < 511) nsum += trk[tg * 8 + lab[t + 1]];
      }
    }
    float se = alpha * __expf(endc);
    se += dppf<QP1>(se); se += dppf<QP2>(se); se += dppf<ROR4>(se);
    float logZ = logZacc + __logf(se);
    nsum += dppf<QP1>(nsum); nsum += dppf<QP2>(nsum);
    nsum += dppf<ROR4>(nsum); nsum += dppf<ROR8>(nsum);
    if (l16 == 0) {
      float num = nsum + startT[k * 8 + lab[0]] + endT[k * 8 + lab[511]];
      atomicAdd(d_out, logZ - num);
    }
  } else {
    // ------------- viterbi -------------
    float v = startc + ecur[0];
    int pk[8];
#pragma unroll
    for (int kk = 0; kk < 8; ++kk) pk[kk] = c ^ kk;

#pragma unroll 1
    for (int r = 0; r < 4; ++r) {
      if (r < 3) writeRegion((r + 1) & 1);
      if (r < 2) loadRegion(r + 2);
#pragma unroll 1
      for (int t0 = r * 128; t0 < r * 128 + 128; t0 += 8) {
        float enext[8];
        if (t0 + 8 < 512) {
          const float* rg = sEm[((t0 + 8) >> 7) & 1];
#pragma unroll
          for (int i = 0; i < 8; ++i) enext[i] = rg[(((t0 + 8 + i) & 127) * 4 + s) * 8 + c];
        } else {
#pragma unroll
          for (int i = 0; i < 8; ++i) enext[i] = 0.0f;
        }
#pragma unroll
        for (int j = 0; j < 8; ++j) {
          if (t0 == 0 && j == 0) continue;
          float b1 = dppf<QP1>(v), b2 = dppf<QP2>(v), b3 = dppf<QP2>(b1);
          float b4 = dppf<ROR4>(v), b5 = dppf<ROR4>(b1);
          float b6 = dppf<ROR4>(b2), b7 = dppf<ROR4>(b3);
          float c0 = v + Tx[0], c1 = b1 + Tx[1], c2 = b2 + Tx[2], c3 = b3 + Tx[3];
          float c4 = b4 + Tx[4], c5 = b5 + Tx[5], c6 = b6 + Tx[6], c7 = b7 + Tx[7];
          float m0 = fmaxf(fmaxf(c0, c1), c2);
          float m1 = fmaxf(fmaxf(c3, c4), c5);
          float m2 = fmaxf(c6, c7);
          float best = fmaxf(fmaxf(m0, m1), m2);
          int a0 = (c0 == best) ? pk[0] : 8;
          int a1i = (c1 == best) ? pk[1] : 8;
          int a2i = (c2 == best) ? pk[2] : 8;
          int a3i = (c3 == best) ? pk[3] : 8;
          int a4i = (c4 == best) ? pk[4] : 8;
          int a5i = (c5 == best) ? pk[5] : 8;
          int a6i = (c6 == best) ? pk[6] : 8;
          int a7i = (c7 == best) ? pk[7] : 8;
          int arg = min(min(min(a0, a1i), min(a2i, a3i)),
                        min(min(a4i, a5i), min(a6i, a7i)));
          v = best + ecur[j];
          int w = arg << (3 * c);
          w |= dppi<QP1>(w); w |= dppi<QP2>(w); w |= dppi<ROR4>(w);
          if (l16 == 0) sBPp[(t0 + j) * 4 + s] = w;
        }
#pragma unroll
        for (int i = 0; i < 8; ++i) ecur[i] = enext[i];
      }
    }
    // terminal argmax (first max on ties)
    float lv = v + endc;
    int li = c;
    {
      float ov; int oi; bool take;
      ov = dppf<QP1>(lv); oi = dppi<QP1>(li);
      take = (ov > lv) || (ov == lv && oi < li); lv = take ? ov : lv; li = take ? oi : li;
      ov = dppf<QP2>(lv); oi = dppi<QP2>(li);
      take = (ov > lv) || (ov == lv && oi < li); lv = take ? ov : lv; li = take ? oi : li;
      ov = dppf<ROR4>(lv); oi = dppi<ROR4>(li);
      take = (ov > lv) || (ov == lv && oi < li); lv = take ? ov : lv; li = take ? oi : li;
    }
    __syncthreads();
    if (l16 == 0) {
      int tag = li;
      sTags[s * 512 + 511] = (unsigned char)tag;
      int t = 511;
      while (t >= 1) {
        int n = (t >= 8) ? 8 : t;
        int words[8];
#pragma unroll
        for (int i = 0; i < 8; ++i)
          if (i < n) words[i] = sBPp[(t - i) * 4 + s];
#pragma unroll
        for (int i = 0; i < 8; ++i)
          if (i < n) {
            tag = (words[i] >> (3 * tag)) & 7;
            sTags[s * 512 + t - i - 1] = (unsigned char)tag;
          }
        t -= n;
      }
    }
    __syncthreads();
    float* outp = d_out + 1 + LOGITS_N + (size_t)sb * 2048;
    for (int u = 0; u < 32; ++u) {
      int idx = u * 64 + lane;
      outp[idx] = (float)sTags[idx];
    }
  }
}

extern "C" void kernel_launch(void* const* d_in, const int* in_sizes, int n_in,
                              void* d_out, int out_size, void* d_ws, size_t ws_size,
                              hipStream_t stream) {
  const float* enc    = (const float*)d_in[0];
  const int*   labels = (const int*)  d_in[1];
  const float* W      = (const float*)d_in[2];
  const float* bias   = (const float*)d_in[3];
  const float* startT = (const float*)d_in[4];
  const float* endT   = (const float*)d_in[5];
  const float* trans  = (const float*)d_in[6];
  float* out = (float*)d_out;
  float* Wt  = (float*)d_ws;   // 24*1024 floats = 96 KB scratch

  init_kernel<<<dim3(3072), dim3(256), 0, stream>>>(W, bias, Wt, out);
  proj_kernel<<<dim3(256), dim3(256), 0, stream>>>(enc, Wt, out);
  crf_kernel<<<dim3(96), dim3(64), 0, stream>>>(labels, startT, endT, trans, out);
}

// Round 5
// 322.718 us; speedup vs baseline: 1.1917x; 1.1599x over previous
//
#include <hip/hip_runtime.h>

#define NB 64
#define NT 512
#define NH 1024
#define NC 8
#define NK 3
#define BT (NB*NT)             // 32768
#define LOGITS_N (NK*BT*NC)    // 786432

// DPP controls
#define QP1  0xB1   // quad_perm [1,0,3,2] -> lane^1
#define QP2  0x4E   // quad_perm [2,3,0,1] -> lane^2
#define ROR4 0x124  // row_ror:4 -> flips lane bit2; bit3 (dup) flip harmless
#define ROR8 0x128  // row_ror:8 -> lane^8 within 16-row

template<int CTRL>
__device__ __forceinline__ float dppf(float x) {
  return __int_as_float(__builtin_amdgcn_update_dpp(0, __float_as_int(x), CTRL, 0xF, 0xF, true));
}
template<int CTRL>
__device__ __forceinline__ int dppi(int x) {
  return __builtin_amdgcn_update_dpp(0, x, CTRL, 0xF, 0xF, true);
}

// ---------- init: bias into logits, zero loss, transpose W -> Wt[h][24] ----
__global__ __launch_bounds__(256) void init_kernel(const float* __restrict__ W,
                                                   const float* __restrict__ bias,
                                                   float* __restrict__ Wt,
                                                   float* __restrict__ out) {
  int i = blockIdx.x * 256 + threadIdx.x;
  if (i < LOGITS_N) {
    int k = i >> 18, c = i & 7;
    out[1 + i] = bias[k * 8 + c];
  }
  if (i < 24 * NH) {
    int h = i / 24, j = i - h * 24;
    int kk = j >> 3, cc = j & 7;
    Wt[i] = W[kk * NC * NH + cc * NH + h];   // Wt[h*24 + j]
  }
  if (i == 0) out[0] = 0.0f;
}

// ---------- proj v7: 1024 blocks = 512 rowblocks(64 rows) x 2 h-halves.
// 256 thr = 4 waves; wave q owns h-quarter [hs*512 + q*128, +128).
// Private per-wave LDS staging -> NO barriers in main loop. W via
// readfirstlane -> s_load. Quarters combined in LDS; halves via atomics.
__global__ __launch_bounds__(256, 4) void proj_kernel(const float* __restrict__ enc,
                                                      const float* __restrict__ Wt,
                                                      float* __restrict__ out) {
  __shared__ float smem[8704];            // 4 waves x 2 bufs x 1088 (64 rows x 17)
  const int tid = threadIdx.x;
  const int lane = tid & 63;
  const int q = tid >> 6;
  const int hs = blockIdx.x & 1;
  const int rb = blockIdx.x >> 1;         // 0..511
  const int row0 = rb * 64;
  const int hbase = hs * 512 + q * 128;
  const float* eb = enc + (size_t)row0 * 1024 + hbase;
  float* sE0 = smem + q * 2176;

  float acc[24];
#pragma unroll
  for (int j = 0; j < 24; ++j) acc[j] = 0.0f;

  float4 pfc[4], pfn[4];
  auto loadChunk = [&](int ch, float4* pf) {
#pragma unroll
    for (int s = 0; s < 4; ++s) {
      int f = lane + 64 * s;
      pf[s] = *(const float4*)(eb + (size_t)(f >> 2) * 1024 + ch * 16 + (f & 3) * 4);
    }
  };
  auto stageChunk = [&](int buf, const float4* pf) {
    float* d = sE0 + buf * 1088;
#pragma unroll
    for (int s = 0; s < 4; ++s) {
      int f = lane + 64 * s;
      float* p = d + (f >> 2) * 17 + (f & 3) * 4;
      p[0] = pf[s].x; p[1] = pf[s].y; p[2] = pf[s].z; p[3] = pf[s].w;
    }
  };

  loadChunk(0, pfc);
  stageChunk(0, pfc);
  loadChunk(1, pfc);

#pragma unroll 1
  for (int ch = 0; ch < 8; ++ch) {
    const int buf = ch & 1;
    if (ch < 6) loadChunk(ch + 2, pfn);
    const float* wrow = Wt + __builtin_amdgcn_readfirstlane((hbase + ch * 16) * 24);
    const float* er = sE0 + buf * 1088 + lane * 17;
#pragma unroll 4
    for (int h = 0; h < 16; ++h) {
      float e = er[h];
      const float* wr = wrow + h * 24;
#pragma unroll
      for (int j = 0; j < 24; ++j)
        acc[j] = fmaf(e, wr[j], acc[j]);
    }
    if (ch < 7) {
      stageChunk(buf ^ 1, pfc);
#pragma unroll
      for (int s = 0; s < 4; ++s) pfc[s] = pfn[s];
    }
  }

  // combine quarters in LDS (reuse smem), then halves via atomics
  __syncthreads();
  float* sp = smem + q * 1792;            // 64 rows x 28
#pragma unroll
  for (int j4 = 0; j4 < 24; j4 += 4)
    *(float4*)&sp[lane * 28 + j4] = make_float4(acc[j4], acc[j4+1], acc[j4+2], acc[j4+3]);
  __syncthreads();

  const int r = tid >> 2, j0 = (tid & 3) * 6;
#pragma unroll
  for (int u = 0; u < 6; ++u) {
    int j = j0 + u;
    float s = smem[0 * 1792 + r * 28 + j] + smem[1 * 1792 + r * 28 + j]
            + smem[2 * 1792 + r * 28 + j] + smem[3 * 1792 + r * 28 + j];
    atomicAdd(&out[1 + (size_t)(j >> 3) * (BT * 8) + (size_t)(row0 + r) * 8 + (j & 7)], s);
  }
}

// ---------- CRF: blocks 0..47 forward+loss, 48..95 viterbi+preds ----------
// (unchanged from round 4 — frozen to isolate the proj delta)
__global__ __launch_bounds__(64) void crf_kernel(const int* __restrict__ labels,
                                                 const float* __restrict__ startT,
                                                 const float* __restrict__ endT,
                                                 const float* __restrict__ trans,
                                                 float* __restrict__ d_out) {
  __shared__ float sEm[2][128 * 32];       // [buf][(t'*4+s)*8+c]  32 KB
  __shared__ int sBPp[512 * 4];            // vit: packed 3-bit args [t][s]  8 KB
  __shared__ unsigned char sTags[2048];    // vit: [s*512+t]  2 KB

  const int lane = threadIdx.x;
  const int l16 = lane & 15;
  const int s = lane >> 4;
  const int c = l16 & 7;
  const int role = (blockIdx.x < 48) ? 0 : 1;
  const int sb = role ? (blockIdx.x - 48) : blockIdx.x;
  const int seq = sb * 4 + s;
  const int k = seq >> 6, b = seq & 63;

  const float* out1 = d_out + 1;
  const float* embase = out1 + (size_t)k * (BT * 8) + (size_t)(b * 512) * 8;
  const float* trk = trans + k * 64;

  float Tx[8];
#pragma unroll
  for (int kk = 0; kk < 8; ++kk) Tx[kk] = trk[(c ^ kk) * 8 + c];
  const float startc = startT[k * 8 + c];
  const float endc = endT[k * 8 + c];

  float4 pre[16];
  auto loadRegion = [&](int r) {
#pragma unroll
    for (int u = 0; u < 16; ++u) {
      int f = u * 16 + l16;
      int t = r * 128 + (f >> 1);
      const float* o = embase + (size_t)t * 8 + (f & 1) * 4;
      pre[u] = make_float4(o[0], o[1], o[2], o[3]);
    }
  };
  auto writeRegion = [&](int buf) {
    float* dst = sEm[buf];
#pragma unroll
    for (int u = 0; u < 16; ++u) {
      int f = u * 16 + l16;
      *(float4*)&dst[((f >> 1) * 4 + s) * 8 + (f & 1) * 4] = pre[u];
    }
  };

  loadRegion(0);
  writeRegion(0);
  loadRegion(1);

  float ecur[8];
#pragma unroll
  for (int i = 0; i < 8; ++i) ecur[i] = sEm[0][(i * 4 + s) * 8 + c];

  if (role == 0) {
    float Mx[8];
#pragma unroll
    for (int kk = 0; kk < 8; ++kk) Mx[kk] = __expf(Tx[kk]);
    float alpha = __expf(startc + ecur[0]);
    float logZacc = 0.0f, nsum = 0.0f;
    const int* lab = labels + b * (NK * NT) + k * NT;

#pragma unroll 1
    for (int r = 0; r < 4; ++r) {
      if (r < 3) writeRegion((r + 1) & 1);
      if (r < 2) loadRegion(r + 2);
#pragma unroll 1
      for (int t0 = r * 128; t0 < r * 128 + 128; t0 += 8) {
        float enext[8];
        if (t0 + 8 < 512) {
          const float* rg = sEm[((t0 + 8) >> 7) & 1];
#pragma unroll
          for (int i = 0; i < 8; ++i) enext[i] = rg[(((t0 + 8 + i) & 127) * 4 + s) * 8 + c];
        } else {
#pragma unroll
          for (int i = 0; i < 8; ++i) enext[i] = 0.0f;
        }
        float ex[8];
#pragma unroll
        for (int i = 0; i < 8; ++i) ex[i] = __expf(ecur[i]);
#pragma unroll
        for (int j = 0; j < 8; ++j) {
          if (t0 == 0 && j == 0) continue;
          float a1 = dppf<QP1>(alpha), a2 = dppf<QP2>(alpha), a3 = dppf<QP2>(a1);
          float a4 = dppf<ROR4>(alpha), a5 = dppf<ROR4>(a1);
          float a6 = dppf<ROR4>(a2), a7 = dppf<ROR4>(a3);
          float s01 = fmaf(a1, Mx[1], alpha * Mx[0]);
          float s23 = fmaf(a3, Mx[3], a2 * Mx[2]);
          float s45 = fmaf(a5, Mx[5], a4 * Mx[4]);
          float s67 = fmaf(a7, Mx[7], a6 * Mx[6]);
          alpha = ((s01 + s23) + (s45 + s67)) * ex[j];
        }
        float sum = alpha;
        sum += dppf<QP1>(sum); sum += dppf<QP2>(sum); sum += dppf<ROR4>(sum);
        logZacc += __logf(sum);
        alpha *= (1.0f / sum);
#pragma unroll
        for (int i = 0; i < 8; ++i) ecur[i] = enext[i];
      }
      const float* rg = sEm[r & 1];
#pragma unroll 1
      for (int i = 0; i < 8; ++i) {
        int t = r * 128 + l16 + i * 16;
        int tg = lab[t];
        nsum += rg[((t & 127) * 4 + s) * 8 + tg];
        if (t < 511) nsum += trk[tg * 8 + lab[t + 1]];
      }
    }
    float se = alpha * __expf(endc);
    se += dppf<QP1>(se); se += dppf<QP2>(se); se += dppf<ROR4>(se);
    float logZ = logZacc + __logf(se);
    nsum += dppf<QP1>(nsum); nsum += dppf<QP2>(nsum);
    nsum += dppf<ROR4>(nsum); nsum += dppf<ROR8>(nsum);
    if (l16 == 0) {
      float num = nsum + startT[k * 8 + lab[0]] + endT[k * 8 + lab[511]];
      atomicAdd(d_out, logZ - num);
    }
  } else {
    float v = startc + ecur[0];
    int pk[8];
#pragma unroll
    for (int kk = 0; kk < 8; ++kk) pk[kk] = c ^ kk;

#pragma unroll 1
    for (int r = 0; r < 4; ++r) {
      if (r < 3) writeRegion((r + 1) & 1);
      if (r < 2) loadRegion(r + 2);
#pragma unroll 1
      for (int t0 = r * 128; t0 < r * 128 + 128; t0 += 8) {
        float enext[8];
        if (t0 + 8 < 512) {
          const float* rg = sEm[((t0 + 8) >> 7) & 1];
#pragma unroll
          for (int i = 0; i < 8; ++i) enext[i] = rg[(((t0 + 8 + i) & 127) * 4 + s) * 8 + c];
        } else {
#pragma unroll
          for (int i = 0; i < 8; ++i) enext[i] = 0.0f;
        }
#pragma unroll
        for (int j = 0; j < 8; ++j) {
          if (t0 == 0 && j == 0) continue;
          float b1 = dppf<QP1>(v), b2 = dppf<QP2>(v), b3 = dppf<QP2>(b1);
          float b4 = dppf<ROR4>(v), b5 = dppf<ROR4>(b1);
          float b6 = dppf<ROR4>(b2), b7 = dppf<ROR4>(b3);
          float c0 = v + Tx[0], c1 = b1 + Tx[1], c2 = b2 + Tx[2], c3 = b3 + Tx[3];
          float c4 = b4 + Tx[4], c5 = b5 + Tx[5], c6 = b6 + Tx[6], c7 = b7 + Tx[7];
          float m0 = fmaxf(fmaxf(c0, c1), c2);
          float m1 = fmaxf(fmaxf(c3, c4), c5);
          float m2 = fmaxf(c6, c7);
          float best = fmaxf(fmaxf(m0, m1), m2);
          int a0 = (c0 == best) ? pk[0] : 8;
          int a1i = (c1 == best) ? pk[1] : 8;
          int a2i = (c2 == best) ? pk[2] : 8;
          int a3i = (c3 == best) ? pk[3] : 8;
          int a4i = (c4 == best) ? pk[4] : 8;
          int a5i = (c5 == best) ? pk[5] : 8;
          int a6i = (c6 == best) ? pk[6] : 8;
          int a7i = (c7 == best) ? pk[7] : 8;
          int arg = min(min(min(a0, a1i), min(a2i, a3i)),
                        min(min(a4i, a5i), min(a6i, a7i)));
          v = best + ecur[j];
          int w = arg << (3 * c);
          w |= dppi<QP1>(w); w |= dppi<QP2>(w); w |= dppi<ROR4>(w);
          if (l16 == 0) sBPp[(t0 + j) * 4 + s] = w;
        }
#pragma unroll
        for (int i = 0; i < 8; ++i) ecur[i] = enext[i];
      }
    }
    float lv = v + endc;
    int li = c;
    {
      float ov; int oi; bool take;
      ov = dppf<QP1>(lv); oi = dppi<QP1>(li);
      take = (ov > lv) || (ov == lv && oi < li); lv = take ? ov : lv; li = take ? oi : li;
      ov = dppf<QP2>(lv); oi = dppi<QP2>(li);
      take = (ov > lv) || (ov == lv && oi < li); lv = take ? ov : lv; li = take ? oi : li;
      ov = dppf<ROR4>(lv); oi = dppi<ROR4>(li);
      take = (ov > lv) || (ov == lv && oi < li); lv = take ? ov : lv; li = take ? oi : li;
    }
    __syncthreads();
    if (l16 == 0) {
      int tag = li;
      sTags[s * 512 + 511] = (unsigned char)tag;
      int t = 511;
      while (t >= 1) {
        int n = (t >= 8) ? 8 : t;
        int words[8];
#pragma unroll
        for (int i = 0; i < 8; ++i)
          if (i < n) words[i] = sBPp[(t - i) * 4 + s];
#pragma unroll
        for (int i = 0; i < 8; ++i)
          if (i < n) {
            tag = (words[i] >> (3 * tag)) & 7;
            sTags[s * 512 + t - i - 1] = (unsigned char)tag;
          }
        t -= n;
      }
    }
    __syncthreads();
    float* outp = d_out + 1 + LOGITS_N + (size_t)sb * 2048;
    for (int u = 0; u < 32; ++u) {
      int idx = u * 64 + lane;
      outp[idx] = (float)sTags[idx];
    }
  }
}

extern "C" void kernel_launch(void* const* d_in, const int* in_sizes, int n_in,
                              void* d_out, int out_size, void* d_ws, size_t ws_size,
                              hipStream_t stream) {
  const float* enc    = (const float*)d_in[0];
  const int*   labels = (const int*)  d_in[1];
  const float* W      = (const float*)d_in[2];
  const float* bias   = (const float*)d_in[3];
  const float* startT = (const float*)d_in[4];
  const float* endT   = (const float*)d_in[5];
  const float* trans  = (const float*)d_in[6];
  float* out = (float*)d_out;
  float* Wt  = (float*)d_ws;   // 24*1024 floats = 96 KB scratch

  init_kernel<<<dim3(3072), dim3(256), 0, stream>>>(W, bias, Wt, out);
  proj_kernel<<<dim3(1024), dim3(256), 0, stream>>>(enc, Wt, out);
  crf_kernel<<<dim3(96), dim3(64), 0, stream>>>(labels, startT, endT, trans, out);
}

// Round 6
// 257.185 us; speedup vs baseline: 1.4953x; 1.2548x over previous
//
#include <hip/hip_runtime.h>

#define NB 64
#define NT 512
#define NH 1024
#define NC 8
#define NK 3
#define BT (NB*NT)             // 32768
#define LOGITS_N (NK*BT*NC)    // 786432

// DPP controls
#define QP1  0xB1   // quad_perm [1,0,3,2] -> lane^1
#define QP2  0x4E   // quad_perm [2,3,0,1] -> lane^2
#define ROR4 0x124  // row_ror:4  -> lane^4 (may flip bit3: only safe when value replicated across 8-groups)
#define ROR8 0x128  // row_ror:8  -> exact lane^8 within 16-row
#define HM   0x141  // row_half_mirror -> exact lane^7 within 8

template<int CTRL>
__device__ __forceinline__ float dppf(float x) {
  return __int_as_float(__builtin_amdgcn_update_dpp(0, __float_as_int(x), CTRL, 0xF, 0xF, true));
}
template<int CTRL>
__device__ __forceinline__ int dppi(int x) {
  return __builtin_amdgcn_update_dpp(0, x, CTRL, 0xF, 0xF, true);
}

// ---------- init: bias into logits, zero loss, transpose W -> Wt[h][24] ----
__global__ __launch_bounds__(256) void init_kernel(const float* __restrict__ W,
                                                   const float* __restrict__ bias,
                                                   float* __restrict__ Wt,
                                                   float* __restrict__ out) {
  int i = blockIdx.x * 256 + threadIdx.x;
  if (i < LOGITS_N) {
    int k = i >> 18, c = i & 7;
    out[1 + i] = bias[k * 8 + c];
  }
  if (i < 24 * NH) {
    int h = i / 24, j = i - h * 24;
    int kk = j >> 3, cc = j & 7;
    Wt[i] = W[kk * NC * NH + cc * NH + h];   // Wt[h*24 + j]
  }
  if (i == 0) out[0] = 0.0f;
}

// ---------- proj v7 (unchanged from round 5) --------------------------------
__global__ __launch_bounds__(256, 4) void proj_kernel(const float* __restrict__ enc,
                                                      const float* __restrict__ Wt,
                                                      float* __restrict__ out) {
  __shared__ float smem[8704];
  const int tid = threadIdx.x;
  const int lane = tid & 63;
  const int q = tid >> 6;
  const int hs = blockIdx.x & 1;
  const int rb = blockIdx.x >> 1;
  const int row0 = rb * 64;
  const int hbase = hs * 512 + q * 128;
  const float* eb = enc + (size_t)row0 * 1024 + hbase;
  float* sE0 = smem + q * 2176;

  float acc[24];
#pragma unroll
  for (int j = 0; j < 24; ++j) acc[j] = 0.0f;

  float4 pfc[4], pfn[4];
  auto loadChunk = [&](int ch, float4* pf) {
#pragma unroll
    for (int s = 0; s < 4; ++s) {
      int f = lane + 64 * s;
      pf[s] = *(const float4*)(eb + (size_t)(f >> 2) * 1024 + ch * 16 + (f & 3) * 4);
    }
  };
  auto stageChunk = [&](int buf, const float4* pf) {
    float* d = sE0 + buf * 1088;
#pragma unroll
    for (int s = 0; s < 4; ++s) {
      int f = lane + 64 * s;
      float* p = d + (f >> 2) * 17 + (f & 3) * 4;
      p[0] = pf[s].x; p[1] = pf[s].y; p[2] = pf[s].z; p[3] = pf[s].w;
    }
  };

  loadChunk(0, pfc);
  stageChunk(0, pfc);
  loadChunk(1, pfc);

#pragma unroll 1
  for (int ch = 0; ch < 8; ++ch) {
    const int buf = ch & 1;
    if (ch < 6) loadChunk(ch + 2, pfn);
    const float* wrow = Wt + __builtin_amdgcn_readfirstlane((hbase + ch * 16) * 24);
    const float* er = sE0 + buf * 1088 + lane * 17;
#pragma unroll 4
    for (int h = 0; h < 16; ++h) {
      float e = er[h];
      const float* wr = wrow + h * 24;
#pragma unroll
      for (int j = 0; j < 24; ++j)
        acc[j] = fmaf(e, wr[j], acc[j]);
    }
    if (ch < 7) {
      stageChunk(buf ^ 1, pfc);
#pragma unroll
      for (int s = 0; s < 4; ++s) pfc[s] = pfn[s];
    }
  }

  __syncthreads();
  float* sp = smem + q * 1792;
#pragma unroll
  for (int j4 = 0; j4 < 24; j4 += 4)
    *(float4*)&sp[lane * 28 + j4] = make_float4(acc[j4], acc[j4+1], acc[j4+2], acc[j4+3]);
  __syncthreads();

  const int r = tid >> 2, j0 = (tid & 3) * 6;
#pragma unroll
  for (int u = 0; u < 6; ++u) {
    int j = j0 + u;
    float s = smem[0 * 1792 + r * 28 + j] + smem[1 * 1792 + r * 28 + j]
            + smem[2 * 1792 + r * 28 + j] + smem[3 * 1792 + r * 28 + j];
    atomicAdd(&out[1 + (size_t)(j >> 3) * (BT * 8) + (size_t)(row0 + r) * 8 + (j & 7)], s);
  }
}

// ---------- CRF v6: chunk-parallel scan --------------------------------------
// 384 blocks x 512 thr. blocks 0..191: forward+loss (seq=blockIdx);
// 192..383: viterbi+preds. 1 seq per block; 32 chunks of 16 transitions.
// Phase1: 8 waves build 8x8 chunk transfer matrices (lane=(p,c), DPP within 8).
// Phase2: wave0 32-step scan; fwd waves1-7 do numerator concurrently.
// Vit: exact bp recompute from boundary vectors (tie-exact), parallel backtrace.
__global__ __launch_bounds__(512) void crf_kernel(const int* __restrict__ labels,
                                                  const float* __restrict__ startT,
                                                  const float* __restrict__ endT,
                                                  const float* __restrict__ trans,
                                                  float* __restrict__ d_out) {
  __shared__ float sA[32 * 64];          // chunk matrices [i][p][c]
  __shared__ float sVB[32 * 8];          // vit boundary vectors
  __shared__ int   sBP[512];             // vit packed bp words
  __shared__ int   sMap[32 * 8];         // vit exit->entry maps
  __shared__ int   sEnt[32];             // vit chunk entry states
  __shared__ float sRed[32];             // fwd numerator partials
  __shared__ unsigned char sTags[512];
  __shared__ int sTerm;

  const int tid = threadIdx.x;
  const int lane = tid & 63;
  const int w = tid >> 6;
  const int c = lane & 7;
  const int p = (lane >> 3) & 7;
  const int role = (blockIdx.x >= 192);
  const int seq = role ? blockIdx.x - 192 : blockIdx.x;
  const int k = seq >> 6, b = seq & 63;
  const float* em = d_out + 1 + ((size_t)k * BT + (size_t)b * 512) * 8;
  const float* trk = trans + k * 64;
  const int* lab = labels + b * (NK * NT) + k * NT;

  float Txc[8];
#pragma unroll
  for (int kk = 0; kk < 8; ++kk) Txc[kk] = trk[(c ^ kk) * 8 + c];
  const float Tpc = trk[p * 8 + c];
  const float startc = startT[k * 8 + c];
  const float endc = endT[k * 8 + c];

  if (!role) {
    // ========================= FORWARD (logZ + loss) ========================
    float Mxc[8];
#pragma unroll
    for (int kk = 0; kk < 8; ++kk) Mxc[kk] = __expf(Txc[kk]);

    // phase 1: linear-domain chunk matrices, constant 2^-32 renorm at step 8
#pragma unroll 1
    for (int it = 0; it < 4; ++it) {
      const int i = w * 4 + it;
      const int t0 = i * 16;
      const int te = (t0 + 16 < 512) ? (t0 + 16) : 511;
      float EX[16];
      EX[0] = em[(t0 + 1) * 8 + c];             // raw em for init
#pragma unroll
      for (int j = 1; j < 16; ++j) {
        int t = t0 + 1 + j;
        EX[j] = (t <= te) ? __expf(em[t * 8 + c]) : 1.0f;
      }
      float V = __expf(Tpc + EX[0]);
#pragma unroll
      for (int j = 1; j < 16; ++j) {
        int t = t0 + 1 + j;
        if (t <= te) {
          float x1 = dppf<QP1>(V), x2 = dppf<QP2>(V), x3 = dppf<QP2>(x1);
          float x7 = dppf<HM>(V), x6 = dppf<QP1>(x7), x5 = dppf<QP2>(x7), x4 = dppf<QP2>(x6);
          float s01 = fmaf(x1, Mxc[1], V * Mxc[0]);
          float s23 = fmaf(x3, Mxc[3], x2 * Mxc[2]);
          float s45 = fmaf(x5, Mxc[5], x4 * Mxc[4]);
          float s67 = fmaf(x7, Mxc[7], x6 * Mxc[6]);
          V = ((s01 + s23) + (s45 + s67)) * EX[j];
        }
        if (j == 8) V *= 0x1p-32f;              // exact pow2 renorm (uniform)
      }
      sA[i * 64 + lane] = V;
    }
    __syncthreads();

    float logZ = 0.0f;
    if (w == 0) {
      // phase 2: 32-step alpha scan
      float al = __expf(startc + em[c]);
      float lz = 0.0f;
#pragma unroll 1
      for (int i = 0; i < 32; ++i) {
        const float* Ai = &sA[i * 64];
        float A0 = Ai[(c ^ 0) * 8 + c], A1 = Ai[(c ^ 1) * 8 + c];
        float A2 = Ai[(c ^ 2) * 8 + c], A3 = Ai[(c ^ 3) * 8 + c];
        float A4 = Ai[(c ^ 4) * 8 + c], A5 = Ai[(c ^ 5) * 8 + c];
        float A6 = Ai[(c ^ 6) * 8 + c], A7 = Ai[(c ^ 7) * 8 + c];
        float a1 = dppf<QP1>(al), a2 = dppf<QP2>(al), a3 = dppf<QP2>(a1);
        float a4 = dppf<ROR4>(al), a5 = dppf<ROR4>(a1), a6 = dppf<ROR4>(a2), a7 = dppf<ROR4>(a3);
        float s01 = fmaf(a1, A1, al * A0);
        float s23 = fmaf(a3, A3, a2 * A2);
        float s45 = fmaf(a5, A5, a4 * A4);
        float s67 = fmaf(a7, A7, a6 * A6);
        float s = (s01 + s23) + (s45 + s67);
        float ss = s;
        ss += dppf<QP1>(ss); ss += dppf<QP2>(ss); ss += dppf<ROR4>(ss);
        lz += __logf(ss);
        al = s * (1.0f / ss);
      }
      float se = al * __expf(endc);
      se += dppf<QP1>(se); se += dppf<QP2>(se); se += dppf<ROR4>(se);
      logZ = lz + __logf(se) + 1024.0f * 0.69314718055994531f;  // 32 chunks x 32 ln2
    } else {
      // phase 2 (waves 1-7): gold-path numerator
      int idx = (w - 1) * 64 + lane;            // 0..447
      float ns = 0.0f;
      {
        int tg = lab[idx];
        ns += em[(size_t)idx * 8 + tg] + trk[tg * 8 + lab[idx + 1]];
      }
      if (idx < 64) {
        int t = idx + 448;
        int tg = lab[t];
        ns += em[(size_t)t * 8 + tg];
        if (t < 511) ns += trk[tg * 8 + lab[t + 1]];
      }
      ns += dppf<QP1>(ns); ns += dppf<QP2>(ns); ns += dppf<HM>(ns); ns += dppf<ROR8>(ns);
      if ((lane & 15) == 0) sRed[(w - 1) * 4 + (lane >> 4)] = ns;
    }
    __syncthreads();
    if (tid == 0) {
      float num = startT[k * 8 + lab[0]] + endT[k * 8 + lab[511]];
#pragma unroll
      for (int u = 0; u < 28; ++u) num += sRed[u];
      atomicAdd(d_out, logZ - num);
    }
  } else {
    // ========================= VITERBI (preds) ==============================
    // phase 1: max-plus chunk matrices
#pragma unroll 1
    for (int it = 0; it < 4; ++it) {
      const int i = w * 4 + it;
      const int t0 = i * 16;
      const int te = (t0 + 16 < 512) ? (t0 + 16) : 511;
      float emv[16];
#pragma unroll
      for (int j = 0; j < 16; ++j) {
        int t = t0 + 1 + j;
        emv[j] = (t <= te) ? em[t * 8 + c] : 0.0f;
      }
      float V = Tpc + emv[0];
#pragma unroll
      for (int j = 1; j < 16; ++j) {
        int t = t0 + 1 + j;
        if (t <= te) {
          float x1 = dppf<QP1>(V), x2 = dppf<QP2>(V), x3 = dppf<QP2>(x1);
          float x7 = dppf<HM>(V), x6 = dppf<QP1>(x7), x5 = dppf<QP2>(x7), x4 = dppf<QP2>(x6);
          float c0 = V + Txc[0], c1 = x1 + Txc[1], c2 = x2 + Txc[2], c3 = x3 + Txc[3];
          float c4 = x4 + Txc[4], c5 = x5 + Txc[5], c6 = x6 + Txc[6], c7 = x7 + Txc[7];
          float m0 = fmaxf(fmaxf(c0, c1), c2);
          float m1 = fmaxf(fmaxf(c3, c4), c5);
          float m2 = fmaxf(c6, c7);
          V = fmaxf(fmaxf(m0, m1), m2) + emv[j];
        }
      }
      sA[i * 64 + lane] = V;
    }
    __syncthreads();

    // phase 2: v scan (wave 0), store boundary vectors
    if (w == 0) {
      float v = startc + em[c];
#pragma unroll 1
      for (int i = 0; i < 32; ++i) {
        if (lane < 8) sVB[i * 8 + c] = v;
        const float* Ai = &sA[i * 64];
        float A0 = Ai[(c ^ 0) * 8 + c], A1 = Ai[(c ^ 1) * 8 + c];
        float A2 = Ai[(c ^ 2) * 8 + c], A3 = Ai[(c ^ 3) * 8 + c];
        float A4 = Ai[(c ^ 4) * 8 + c], A5 = Ai[(c ^ 5) * 8 + c];
        float A6 = Ai[(c ^ 6) * 8 + c], A7 = Ai[(c ^ 7) * 8 + c];
        float a1 = dppf<QP1>(v), a2 = dppf<QP2>(v), a3 = dppf<QP2>(a1);
        float a4 = dppf<ROR4>(v), a5 = dppf<ROR4>(a1), a6 = dppf<ROR4>(a2), a7 = dppf<ROR4>(a3);
        float c0 = v + A0, c1 = a1 + A1, c2 = a2 + A2, c3 = a3 + A3;
        float c4 = a4 + A4, c5 = a5 + A5, c6 = a6 + A6, c7 = a7 + A7;
        float m0 = fmaxf(fmaxf(c0, c1), c2);
        float m1 = fmaxf(fmaxf(c3, c4), c5);
        float m2 = fmaxf(c6, c7);
        v = fmaxf(fmaxf(m0, m1), m2);
      }
      float lv = v + endc;
      int li = c;
      {
        float ov; int oi; bool take;
        ov = dppf<QP1>(lv); oi = dppi<QP1>(li);
        take = (ov > lv) || (ov == lv && oi < li); lv = take ? ov : lv; li = take ? oi : li;
        ov = dppf<QP2>(lv); oi = dppi<QP2>(li);
        take = (ov > lv) || (ov == lv && oi < li); lv = take ? ov : lv; li = take ? oi : li;
        ov = dppf<ROR4>(lv); oi = dppi<ROR4>(li);
        take = (ov > lv) || (ov == lv && oi < li); lv = take ? ov : lv; li = take ? oi : li;
      }
      if (lane == 0) sTerm = li;
    }
    __syncthreads();

    // phase 3: exact bp recompute, 8 chunk-slots per wave (waves 0-3)
    if (w < 4) {
      const int u = lane >> 3;
      const int i = w * 8 + u;
      const int t0 = i * 16;
      const int te = (t0 + 16 < 512) ? (t0 + 16) : 511;
      float emv[16];
#pragma unroll
      for (int j = 0; j < 16; ++j) {
        int t = t0 + 1 + j;
        emv[j] = (t <= te) ? em[t * 8 + c] : 0.0f;
      }
      float v = sVB[i * 8 + c];
#pragma unroll
      for (int j = 0; j < 16; ++j) {
        int t = t0 + 1 + j;
        if (t <= te) {
          float x1 = dppf<QP1>(v), x2 = dppf<QP2>(v), x3 = dppf<QP2>(x1);
          float x7 = dppf<HM>(v), x6 = dppf<QP1>(x7), x5 = dppf<QP2>(x7), x4 = dppf<QP2>(x6);
          float c0 = v + Txc[0], c1 = x1 + Txc[1], c2 = x2 + Txc[2], c3 = x3 + Txc[3];
          float c4 = x4 + Txc[4], c5 = x5 + Txc[5], c6 = x6 + Txc[6], c7 = x7 + Txc[7];
          float m0 = fmaxf(fmaxf(c0, c1), c2);
          float m1 = fmaxf(fmaxf(c3, c4), c5);
          float m2 = fmaxf(c6, c7);
          float best = fmaxf(fmaxf(m0, m1), m2);
          int a0 = (c0 == best) ? (c ^ 0) : 8;
          int a1i = (c1 == best) ? (c ^ 1) : 8;
          int a2i = (c2 == best) ? (c ^ 2) : 8;
          int a3i = (c3 == best) ? (c ^ 3) : 8;
          int a4i = (c4 == best) ? (c ^ 4) : 8;
          int a5i = (c5 == best) ? (c ^ 5) : 8;
          int a6i = (c6 == best) ? (c ^ 6) : 8;
          int a7i = (c7 == best) ? (c ^ 7) : 8;
          int arg = min(min(min(a0, a1i), min(a2i, a3i)),
                        min(min(a4i, a5i), min(a6i, a7i)));
          v = best + emv[j];
          int wd = arg << (3 * c);
          wd |= dppi<QP1>(wd); wd |= dppi<QP2>(wd); wd |= dppi<HM>(wd);
          if ((lane & 7) == 0) sBP[t] = wd;
        }
      }
    }
    __syncthreads();

    // phase 4a: per-chunk exit->entry maps (all 8 exit states in parallel)
    if (w < 4) {
      const int u = lane >> 3;
      const int i = w * 8 + u;
      const int t0 = i * 16;
      const int te = (t0 + 16 < 512) ? (t0 + 16) : 511;
      int tag = c;
#pragma unroll
      for (int j = 16; j >= 1; --j) {
        int t = t0 + j;
        if (t <= te) tag = (sBP[t] >> (3 * tag)) & 7;
      }
      sMap[i * 8 + c] = tag;
    }
    __syncthreads();
    // phase 4b: compose maps -> chunk entry states
    if (tid == 0) {
      int cur = sTerm;
#pragma unroll 1
      for (int i = 31; i >= 0; --i) { cur = sMap[i * 8 + cur]; sEnt[i] = cur; }
    }
    __syncthreads();
    // phase 4c: emit tags per chunk (32 parallel lanes)
    if (w == 0 && lane < 32) {
      const int i = lane;
      const int t0 = i * 16;
      const int te = (t0 + 16 < 512) ? (t0 + 16) : 511;
      int tag = (i == 31) ? sTerm : sEnt[i + 1];
      if (i == 31) sTags[511] = (unsigned char)tag;
#pragma unroll
      for (int j = 16; j >= 1; --j) {
        int t = t0 + j;
        if (t <= te) { tag = (sBP[t] >> (3 * tag)) & 7; sTags[t - 1] = (unsigned char)tag; }
      }
    }
    __syncthreads();
    // phase 5: coalesced pred store
    float* outp = d_out + 1 + LOGITS_N + (size_t)seq * 512;
    outp[tid] = (float)sTags[tid];
  }
}

extern "C" void kernel_launch(void* const* d_in, const int* in_sizes, int n_in,
                              void* d_out, int out_size, void* d_ws, size_t ws_size,
                              hipStream_t stream) {
  const float* enc    = (const float*)d_in[0];
  const int*   labels = (const int*)  d_in[1];
  const float* W      = (const float*)d_in[2];
  const float* bias   = (const float*)d_in[3];
  const float* startT = (const float*)d_in[4];
  const float* endT   = (const float*)d_in[5];
  const float* trans  = (const float*)d_in[6];
  float* out = (float*)d_out;
  float* Wt  = (float*)d_ws;   // 24*1024 floats = 96 KB scratch

  init_kernel<<<dim3(3072), dim3(256), 0, stream>>>(W, bias, Wt, out);
  proj_kernel<<<dim3(1024), dim3(256), 0, stream>>>(enc, Wt, out);
  crf_kernel<<<dim3(384), dim3(512), 0, stream>>>(labels, startT, endT, trans, out);
}